// Round 1
// baseline (398.811 us; speedup 1.0000x reference)
//
#include <hip/hip_runtime.h>
#include <math.h>

#define NN 4096        // nodes
#define DIM 256        // hidden
#define NHEAD 8
#define HDIM 32
#define DFF 512
#define CAP 256        // max tracked nonzeros per row (binomial mean ~41, P(>256) ~ 0)
#define EPS_BN 1e-5f
#define QSCALE 0.0625f // D^-0.5

// ---------------- GEMM: C = scale*(A @ B^T) [+ resid] [relu] ----------------
// A [M,K] row-major, B [Nn,K] row-major, C [M,Nn]. M%64==0, Nn%64==0, K%16==0.
__global__ __launch_bounds__(256) void gemm_nt(
    const float* __restrict__ A, const float* __restrict__ B,
    const float* __restrict__ resid, float* __restrict__ C,
    int M, int Nn, int K, float scale, int relu)
{
    __shared__ float As[16][65];
    __shared__ float Bs[16][65];
    int tid = threadIdx.x;
    int tx = tid & 15, ty = tid >> 4;
    int m0 = blockIdx.y * 64, n0 = blockIdx.x * 64;
    int c = tid & 15, r0 = tid >> 4;
    float acc[4][4] = {};
    for (int k0 = 0; k0 < K; k0 += 16) {
        #pragma unroll
        for (int rr = 0; rr < 4; ++rr) {
            int r = r0 + rr * 16;
            As[c][r] = A[(size_t)(m0 + r) * K + k0 + c];
            Bs[c][r] = B[(size_t)(n0 + r) * K + k0 + c];
        }
        __syncthreads();
        #pragma unroll
        for (int k = 0; k < 16; ++k) {
            float a4[4], b4[4];
            #pragma unroll
            for (int i = 0; i < 4; ++i) a4[i] = As[k][ty * 4 + i];
            #pragma unroll
            for (int j = 0; j < 4; ++j) b4[j] = Bs[k][tx * 4 + j];
            #pragma unroll
            for (int i = 0; i < 4; ++i)
                #pragma unroll
                for (int j = 0; j < 4; ++j)
                    acc[i][j] = fmaf(a4[i], b4[j], acc[i][j]);
        }
        __syncthreads();
    }
    #pragma unroll
    for (int i = 0; i < 4; ++i) {
        int m = m0 + ty * 4 + i;
        #pragma unroll
        for (int j = 0; j < 4; ++j) {
            int n = n0 + tx * 4 + j;
            float v = acc[i][j] * scale;
            if (resid) v += resid[(size_t)m * Nn + n];
            if (relu) v = fmaxf(v, 0.f);
            C[(size_t)m * Nn + n] = v;
        }
    }
}

// ---------------- column reduce (sum + sumsq) over 4096 rows, 256 cols ------
// stage 1: 256 blocks x 256 thr, block b handles rows [16b, 16b+16)
__global__ __launch_bounds__(256) void colreduce_partial(
    const float* __restrict__ x, float* __restrict__ ps, float* __restrict__ pq)
{
    int c = threadIdx.x, b = blockIdx.x;
    float s = 0.f, q = 0.f;
    for (int r = 0; r < 16; ++r) {
        float v = x[(size_t)(b * 16 + r) * DIM + c];
        s += v;
        q += v * v;
    }
    ps[b * DIM + c] = s;
    pq[b * DIM + c] = q;
}

// stage 2 (1 block x 256 thr). mode 0: mean/rstd for BN. mode 1: plain col sum.
__global__ __launch_bounds__(256) void colreduce_final(
    const float* __restrict__ ps, const float* __restrict__ pq,
    float* __restrict__ mean, float* __restrict__ rstd,
    float* __restrict__ plain, int mode)
{
    int c = threadIdx.x;
    float s = 0.f, q = 0.f;
    for (int b = 0; b < 256; ++b) {
        s += ps[b * DIM + c];
        q += pq[b * DIM + c];
    }
    if (mode == 1) {
        plain[c] = s;
    } else {
        float m = s * (1.f / NN);
        float var = q * (1.f / NN) - m * m;
        mean[c] = m;
        rstd[c] = rsqrtf(var + EPS_BN);
    }
}

// ---------------- BN apply: out = (x-mean)*rstd*g + b ----------------------
__global__ __launch_bounds__(256) void bn_apply(
    const float* __restrict__ x, const float* __restrict__ mean,
    const float* __restrict__ rstd, const float* __restrict__ g,
    const float* __restrict__ bsh, float* __restrict__ out)
{
    int c = threadIdx.x;
    size_t i = (size_t)blockIdx.x * DIM + c;
    out[i] = (x[i] - mean[c]) * rstd[c] * g[c] + bsh[c];
}

// ---------------- build per-row nonzero list of A --------------------------
__global__ __launch_bounds__(256) void build_nz(
    const float* __restrict__ A, int* __restrict__ idx,
    float* __restrict__ av, int* __restrict__ cnt)
{
    __shared__ int scnt;
    int tid = threadIdx.x, n = blockIdx.x;
    if (tid == 0) scnt = 0;
    __syncthreads();
    for (int m = tid; m < NN; m += 256) {
        float a = A[(size_t)n * NN + m];
        if (a != 0.0f) {
            int p = atomicAdd(&scnt, 1);
            if (p < CAP) {
                idx[n * CAP + p] = m;
                av[n * CAP + p] = a;
            }
        }
    }
    __syncthreads();
    if (tid == 0) cnt[n] = min(scnt, CAP);
}

// ---------------- sparse-decomposed masked attention -----------------------
// block = one query row n; 8 groups of 32 lanes = (head, d)
// out[n, d*8+h] = (sum_nz (e^{s-mx}-e^{-mx}) v[m,d,h] + e^{-mx} Vsum) / denom
__global__ __launch_bounds__(256) void attn_sparse(
    const float* __restrict__ q, const float* __restrict__ k,
    const float* __restrict__ v, const float* __restrict__ vsum,
    const int* __restrict__ idx, const float* __restrict__ av,
    const int* __restrict__ cnt, float* __restrict__ out)
{
    __shared__ float sS[NHEAD][CAP];
    int tid = threadIdx.x;
    int h = tid >> 5;     // head
    int d = tid & 31;     // dim within head
    int n = blockIdx.x;
    int col = d * NHEAD + h;
    int nnz = cnt[n];
    float qv = q[(size_t)n * DIM + col];

    float rmax = -1e30f;
    for (int j = 0; j < nnz; ++j) {
        int m = idx[n * CAP + j];
        float p = qv * k[(size_t)m * DIM + col];
        #pragma unroll
        for (int o = 16; o > 0; o >>= 1) p += __shfl_xor(p, o, 32);
        float s = p * av[n * CAP + j];
        if (d == 0) sS[h][j] = s;
        rmax = fmaxf(rmax, s);
    }
    float mx = fmaxf(rmax, 0.0f);   // zero-mask entries score 0
    __syncthreads();

    float e0 = expf(-mx);
    float acc = 0.f, dsum = 0.f;
    for (int j = 0; j < nnz; ++j) {
        int m = idx[n * CAP + j];
        float w = expf(sS[h][j] - mx);
        dsum += w;
        acc += (w - e0) * v[(size_t)m * DIM + col];
    }
    float denom = dsum + (float)(NN - nnz) * e0;
    out[(size_t)n * DIM + col] = (acc + e0 * vsum[col]) / denom;
}

// ---------------------------------------------------------------------------
extern "C" void kernel_launch(void* const* d_in, const int* in_sizes, int n_in,
                              void* d_out, int out_size, void* d_ws, size_t ws_size,
                              hipStream_t stream)
{
    const float* A  = (const float*)d_in[0];
    const float* h  = (const float*)d_in[1];
    const float* Wq = (const float*)d_in[2];
    const float* Wk = (const float*)d_in[3];
    const float* Wv = (const float*)d_in[4];
    const float* Wo = (const float*)d_in[5];
    const float* g1 = (const float*)d_in[6];
    const float* b1 = (const float*)d_in[7];
    const float* g2 = (const float*)d_in[8];
    const float* b2 = (const float*)d_in[9];
    const float* W1 = (const float*)d_in[10];
    const float* W2 = (const float*)d_in[11];
    float* out = (float*)d_out;

    char* ws = (char*)d_ws;
    size_t off = 0;
    auto alloc = [&](size_t bytes) -> void* {
        void* p = ws + off;
        off += (bytes + 255) & ~(size_t)255;
        return p;
    };
    const size_t FD = sizeof(float) * (size_t)NN * DIM;   // 4 MB
    float* qb    = (float*)alloc(FD);
    float* kb    = (float*)alloc(FD);
    float* vb    = (float*)alloc(FD);      // t (FFN hidden, 8MB) aliases vb..ao
    float* ao    = (float*)alloc(FD);
    int*   nzidx = (int*)  alloc(sizeof(int)   * (size_t)NN * CAP);
    float* nzav  = (float*)alloc(sizeof(float) * (size_t)NN * CAP);
    int*   nzcnt = (int*)  alloc(sizeof(int)   * NN);
    float* ps    = (float*)alloc(sizeof(float) * 256 * DIM);
    float* pq    = (float*)alloc(sizeof(float) * 256 * DIM);
    float* mean1 = (float*)alloc(sizeof(float) * DIM);
    float* rstd1 = (float*)alloc(sizeof(float) * DIM);
    float* mean2 = (float*)alloc(sizeof(float) * DIM);
    float* rstd2 = (float*)alloc(sizeof(float) * DIM);
    float* vsum  = (float*)alloc(sizeof(float) * DIM);
    // aliases (lifetimes disjoint):
    float* y  = qb;   // post-Wo + residual (BN1 input); q dead after attention
    float* h2 = kb;   // post-BN1; k dead after attention
    float* t  = vb;   // FFN hidden [4096,512] = 8MB, spans vb+ao (both dead)
    float* y2 = qb;   // FFN out + residual (BN2 input); y dead after BN1 apply

    dim3 blk(256);
    dim3 g_qkv(DIM / 64, NN / 64);     // (4, 64)
    dim3 g_ffn1(DFF / 64, NN / 64);    // (8, 64)

    // 1-3: QKV projections (q pre-scaled)
    gemm_nt<<<g_qkv, blk, 0, stream>>>(h, Wq, nullptr, qb, NN, DIM, DIM, QSCALE, 0);
    gemm_nt<<<g_qkv, blk, 0, stream>>>(h, Wk, nullptr, kb, NN, DIM, DIM, 1.f, 0);
    gemm_nt<<<g_qkv, blk, 0, stream>>>(h, Wv, nullptr, vb, NN, DIM, DIM, 1.f, 0);
    // 4: Vsum (column sums of v)
    colreduce_partial<<<256, blk, 0, stream>>>(vb, ps, pq);
    colreduce_final<<<1, blk, 0, stream>>>(ps, pq, nullptr, nullptr, vsum, 1);
    // 5: sparsity structure of A
    build_nz<<<NN, blk, 0, stream>>>(A, nzidx, nzav, nzcnt);
    // 6: sparse-decomposed attention
    attn_sparse<<<NN, blk, 0, stream>>>(qb, kb, vb, vsum, nzidx, nzav, nzcnt, ao);
    // 7: output projection + residual
    gemm_nt<<<g_qkv, blk, 0, stream>>>(ao, Wo, h, y, NN, DIM, DIM, 1.f, 0);
    // 8-9: BN1
    colreduce_partial<<<256, blk, 0, stream>>>(y, ps, pq);
    colreduce_final<<<1, blk, 0, stream>>>(ps, pq, mean1, rstd1, nullptr, 0);
    bn_apply<<<NN, blk, 0, stream>>>(y, mean1, rstd1, g1, b1, h2);
    // 10-11: FFN + residual
    gemm_nt<<<g_ffn1, blk, 0, stream>>>(h2, W1, nullptr, t, NN, DFF, DIM, 1.f, 1);
    gemm_nt<<<g_qkv, blk, 0, stream>>>(t, W2, h2, y2, NN, DIM, DFF, 1.f, 0);
    // 12-13: BN2 -> d_out
    colreduce_partial<<<256, blk, 0, stream>>>(y2, ps, pq);
    colreduce_final<<<1, blk, 0, stream>>>(ps, pq, mean2, rstd2, nullptr, 0);
    bn_apply<<<NN, blk, 0, stream>>>(y2, mean2, rstd2, g2, b2, out);
}

// Round 2
// 265.886 us; speedup vs baseline: 1.4999x; 1.4999x over previous
//
#include <hip/hip_runtime.h>
#include <math.h>

#define NN 4096        // nodes
#define DIM 256        // hidden
#define NHEAD 8
#define HDIM 32
#define DFF 512
#define CAP 256        // max tracked nonzeros per row (mean ~41, P(>256) ~ 0)
#define EPS_BN 1e-5f
#define QSCALE 0.0625f // D^-0.5

// ---------------- GEMM: C = scale*(A @ B^T) [+ resid] [relu] [permN] -------
// A [M,K] row-major, B [Nn,K] row-major. Normal store: C[M,Nn].
// permN store (for QKV head-major): C[((n&7)*M + m)*32 + (n>>3)]
__global__ __launch_bounds__(256) void gemm_nt(
    const float* __restrict__ A, const float* __restrict__ B,
    const float* __restrict__ resid, float* __restrict__ C,
    int M, int Nn, int K, float scale, int relu, int permN)
{
    __shared__ float As[16][65];
    __shared__ float Bs[16][65];
    int tid = threadIdx.x;
    int tx = tid & 15, ty = tid >> 4;
    int m0 = blockIdx.y * 64, n0 = blockIdx.x * 64;
    int c = tid & 15, r0 = tid >> 4;
    float acc[4][4] = {};
    for (int k0 = 0; k0 < K; k0 += 16) {
        #pragma unroll
        for (int rr = 0; rr < 4; ++rr) {
            int r = r0 + rr * 16;
            As[c][r] = A[(size_t)(m0 + r) * K + k0 + c];
            Bs[c][r] = B[(size_t)(n0 + r) * K + k0 + c];
        }
        __syncthreads();
        #pragma unroll
        for (int k = 0; k < 16; ++k) {
            float a4[4], b4[4];
            #pragma unroll
            for (int i = 0; i < 4; ++i) a4[i] = As[k][ty * 4 + i];
            #pragma unroll
            for (int j = 0; j < 4; ++j) b4[j] = Bs[k][tx * 4 + j];
            #pragma unroll
            for (int i = 0; i < 4; ++i)
                #pragma unroll
                for (int j = 0; j < 4; ++j)
                    acc[i][j] = fmaf(a4[i], b4[j], acc[i][j]);
        }
        __syncthreads();
    }
    #pragma unroll
    for (int i = 0; i < 4; ++i) {
        int m = m0 + ty * 4 + i;
        #pragma unroll
        for (int j = 0; j < 4; ++j) {
            int n = n0 + tx * 4 + j;
            float v = acc[i][j] * scale;
            if (resid) v += resid[(size_t)m * Nn + n];
            if (relu) v = fmaxf(v, 0.f);
            if (permN)
                C[(((size_t)(n & 7)) * M + m) * HDIM + (n >> 3)] = v;
            else
                C[(size_t)m * Nn + n] = v;
        }
    }
}

// ---------------- column reduce for BN (sum + sumsq) -----------------------
__global__ __launch_bounds__(256) void colreduce_partial(
    const float* __restrict__ x, float* __restrict__ ps, float* __restrict__ pq)
{
    int c = threadIdx.x, b = blockIdx.x;
    float s = 0.f, q = 0.f;
    for (int r = 0; r < 16; ++r) {
        float v = x[(size_t)(b * 16 + r) * DIM + c];
        s += v;
        q += v * v;
    }
    ps[b * DIM + c] = s;
    pq[b * DIM + c] = q;
}

__global__ __launch_bounds__(256) void colreduce_final(
    const float* __restrict__ ps, const float* __restrict__ pq,
    float* __restrict__ mean, float* __restrict__ rstd)
{
    int c = threadIdx.x;
    float s = 0.f, q = 0.f;
    for (int b = 0; b < 256; ++b) {
        s += ps[b * DIM + c];
        q += pq[b * DIM + c];
    }
    float m = s * (1.f / NN);
    float var = q * (1.f / NN) - m * m;
    mean[c] = m;
    rstd[c] = rsqrtf(var + EPS_BN);
}

__global__ __launch_bounds__(256) void bn_apply(
    const float* __restrict__ x, const float* __restrict__ mean,
    const float* __restrict__ rstd, const float* __restrict__ g,
    const float* __restrict__ bsh, float* __restrict__ out)
{
    int c = threadIdx.x;
    size_t i = (size_t)blockIdx.x * DIM + c;
    out[i] = (x[i] - mean[c]) * rstd[c] * g[c] + bsh[c];
}

// ---------------- vsum over head-major v: vsumh[h][d] = sum_m v[h][m][d] ---
// stage 1: 64 blocks = (c<<3)|h, thread: d=tid&31, r=tid>>5
__global__ __launch_bounds__(256) void vsum_part(
    const float* __restrict__ vh, float* __restrict__ part)
{
    __shared__ float red[8][32];
    int h = blockIdx.x & 7, cchunk = blockIdx.x >> 3;
    int d = threadIdx.x & 31, r = threadIdx.x >> 5;
    const float* vp = vh + ((size_t)h * NN + cchunk * 512) * HDIM + d;
    float s = 0.f;
    for (int m = r; m < 512; m += 8) s += vp[(size_t)m * HDIM];
    red[r][d] = s;
    __syncthreads();
    if (r == 0) {
        float t = 0.f;
        #pragma unroll
        for (int i = 0; i < 8; ++i) t += red[i][d];
        part[(size_t)blockIdx.x * 32 + d] = t;
    }
}

__global__ __launch_bounds__(256) void vsum_final(
    const float* __restrict__ part, float* __restrict__ vsumh)
{
    int tid = threadIdx.x;
    int h = tid >> 5, d = tid & 31;
    float s = 0.f;
    #pragma unroll
    for (int c = 0; c < 8; ++c) s += part[(size_t)((c << 3) | h) * 32 + d];
    vsumh[tid] = s;   // layout [h][d]
}

// ---------------- deterministic per-row nonzero list of A ------------------
__global__ __launch_bounds__(256) void build_nz2(
    const float* __restrict__ A, int* __restrict__ idx,
    float* __restrict__ av, int* __restrict__ cnt)
{
    __shared__ int scan[256];
    int tid = threadIdx.x, n = blockIdx.x;
    const float* row = A + (size_t)n * NN;
    int base = tid * 16;
    int c = 0;
    #pragma unroll
    for (int i = 0; i < 16; ++i) c += (row[base + i] != 0.f) ? 1 : 0;
    scan[tid] = c;
    __syncthreads();
    // Hillis-Steele inclusive scan over 256
    for (int off = 1; off < 256; off <<= 1) {
        int t = (tid >= off) ? scan[tid - off] : 0;
        __syncthreads();
        scan[tid] += t;
        __syncthreads();
    }
    int pos = scan[tid] - c;       // exclusive prefix
    int total = scan[255];
    #pragma unroll
    for (int i = 0; i < 16; ++i) {
        float a = row[base + i];
        if (a != 0.f && pos < CAP) {
            idx[n * CAP + pos] = base + i;
            av[n * CAP + pos] = a;
            ++pos;
        }
    }
    if (tid == 0) cnt[n] = min(total, CAP);
}

// ---------------- sparse masked attention, ILP-restructured ----------------
// qh/kh/vh head-major [H][N][32]. Block = query row n, 256 threads.
__global__ __launch_bounds__(256) void attn2(
    const float* __restrict__ qh, const float* __restrict__ kh,
    const float* __restrict__ vh, const float* __restrict__ vsumh,
    const int* __restrict__ idx, const float* __restrict__ av,
    const int* __restrict__ cnt, float* __restrict__ out)
{
    __shared__ float sQ[NHEAD][HDIM];     // 1 KB
    __shared__ int   sIdx[CAP];           // 1 KB
    __shared__ float sAv[CAP];            // 1 KB
    __shared__ float sS[CAP][NHEAD];      // 8 KB: scores -> (w - e0)
    __shared__ float red[32][NHEAD];      // 1 KB
    __shared__ float sE0[NHEAD], sMx[NHEAD], sRd[NHEAD];

    int tid = threadIdx.x, n = blockIdx.x;
    int nnz = cnt[n];
    {
        int h = tid >> 5, d = tid & 31;
        sQ[h][d] = qh[((size_t)h * NN + n) * HDIM + d];
    }
    for (int j = tid; j < nnz; j += 256) {
        sIdx[j] = idx[n * CAP + j];
        sAv[j]  = av[n * CAP + j];
    }
    __syncthreads();

    // ---- phase 1: scores. task (j = jb + tid>>3, h = tid&7) ----
    int h8 = tid & 7, jr = tid >> 3;
    float4 qreg[8];
    #pragma unroll
    for (int t = 0; t < 8; ++t) qreg[t] = ((const float4*)sQ[h8])[t];
    float lmax = 0.0f;                    // masked entries score exactly 0
    for (int jb = 0; jb < nnz; jb += 32) {
        int j = jb + jr;
        if (j < nnz) {
            int m = sIdx[j];
            const float4* kp = (const float4*)(kh + ((size_t)h8 * NN + m) * HDIM);
            float s = 0.f;
            #pragma unroll
            for (int t = 0; t < 8; ++t) {
                float4 kv = kp[t];
                s += kv.x * qreg[t].x + kv.y * qreg[t].y
                   + kv.z * qreg[t].z + kv.w * qreg[t].w;
            }
            s *= sAv[j];
            sS[j][h8] = s;
            lmax = fmaxf(lmax, s);
        }
    }
    red[jr][h8] = lmax;
    __syncthreads();
    if (jr < 16) red[jr][h8] = fmaxf(red[jr][h8], red[jr + 16][h8]);
    __syncthreads();
    if (jr < 8)  red[jr][h8] = fmaxf(red[jr][h8], red[jr + 8][h8]);
    __syncthreads();
    if (jr < 4)  red[jr][h8] = fmaxf(red[jr][h8], red[jr + 4][h8]);
    __syncthreads();
    if (jr < 2)  red[jr][h8] = fmaxf(red[jr][h8], red[jr + 2][h8]);
    __syncthreads();
    if (jr == 0) {
        float mx = fmaxf(red[0][h8], red[1][h8]);
        sMx[h8] = mx;
        sE0[h8] = __expf(-mx);
    }
    __syncthreads();

    // ---- phase 2: weights + denom ----
    float mx = sMx[h8], e0 = sE0[h8];
    float lsum = 0.f;
    for (int jb = 0; jb < nnz; jb += 32) {
        int j = jb + jr;
        if (j < nnz) {
            float w = __expf(sS[j][h8] - mx);
            lsum += w;
            sS[j][h8] = w - e0;
        }
    }
    red[jr][h8] = lsum;
    __syncthreads();
    if (jr < 16) red[jr][h8] += red[jr + 16][h8];
    __syncthreads();
    if (jr < 8)  red[jr][h8] += red[jr + 8][h8];
    __syncthreads();
    if (jr < 4)  red[jr][h8] += red[jr + 4][h8];
    __syncthreads();
    if (jr < 2)  red[jr][h8] += red[jr + 2][h8];
    __syncthreads();
    if (jr == 0) {
        float den = red[0][h8] + red[1][h8] + (float)(NN - nnz) * e0;
        sRd[h8] = 1.0f / den;
    }
    __syncthreads();

    // ---- phase 3: output. thread (h = tid>>5, d = tid&31) ----
    int h = tid >> 5, d = tid & 31;
    const float* vp = vh + (size_t)h * NN * HDIM + d;
    float acc = 0.f;
    #pragma unroll 4
    for (int j = 0; j < nnz; ++j) {
        acc += sS[j][h] * vp[(size_t)sIdx[j] * HDIM];
    }
    float r = (acc + sE0[h] * vsumh[h * HDIM + d]) * sRd[h];
    out[(size_t)n * DIM + d * NHEAD + h] = r;
}

// ---------------------------------------------------------------------------
extern "C" void kernel_launch(void* const* d_in, const int* in_sizes, int n_in,
                              void* d_out, int out_size, void* d_ws, size_t ws_size,
                              hipStream_t stream)
{
    const float* A  = (const float*)d_in[0];
    const float* h  = (const float*)d_in[1];
    const float* Wq = (const float*)d_in[2];
    const float* Wk = (const float*)d_in[3];
    const float* Wv = (const float*)d_in[4];
    const float* Wo = (const float*)d_in[5];
    const float* g1 = (const float*)d_in[6];
    const float* b1 = (const float*)d_in[7];
    const float* g2 = (const float*)d_in[8];
    const float* b2 = (const float*)d_in[9];
    const float* W1 = (const float*)d_in[10];
    const float* W2 = (const float*)d_in[11];
    float* out = (float*)d_out;

    char* ws = (char*)d_ws;
    size_t off = 0;
    auto alloc = [&](size_t bytes) -> void* {
        void* p = ws + off;
        off += (bytes + 255) & ~(size_t)255;
        return p;
    };
    const size_t FD = sizeof(float) * (size_t)NN * DIM;   // 4 MB
    float* qh    = (float*)alloc(FD);                     // [8][4096][32]
    float* kh    = (float*)alloc(FD);
    float* vh    = (float*)alloc(FD);
    float* ao    = (float*)alloc(FD);                     // attn out [N][D]
    int*   nzidx = (int*)  alloc(sizeof(int)   * (size_t)NN * CAP);
    float* nzav  = (float*)alloc(sizeof(float) * (size_t)NN * CAP);
    int*   nzcnt = (int*)  alloc(sizeof(int)   * NN);
    float* ps    = (float*)alloc(sizeof(float) * 256 * DIM);
    float* pq    = (float*)alloc(sizeof(float) * 256 * DIM);
    float* mean1 = (float*)alloc(sizeof(float) * DIM);
    float* rstd1 = (float*)alloc(sizeof(float) * DIM);
    float* mean2 = (float*)alloc(sizeof(float) * DIM);
    float* rstd2 = (float*)alloc(sizeof(float) * DIM);
    float* vpart = (float*)alloc(sizeof(float) * 64 * 32);
    float* vsumh = (float*)alloc(sizeof(float) * DIM);
    // aliases (lifetimes disjoint):
    float* y  = qh;   // post-Wo + residual (BN1 input); q dead after attention
    float* h2 = kh;   // post-BN1; k dead after attention
    float* t  = vh;   // FFN hidden [4096,512] = 8 MB, spans vh+ao (both dead)
    float* y2 = qh;   // FFN out + residual (BN2 input)

    dim3 blk(256);
    dim3 g_qkv(DIM / 64, NN / 64);     // (4, 64)
    dim3 g_ffn1(DFF / 64, NN / 64);    // (8, 64)

    // QKV projections, head-major stores (q pre-scaled)
    gemm_nt<<<g_qkv, blk, 0, stream>>>(h, Wq, nullptr, qh, NN, DIM, DIM, QSCALE, 0, 1);
    gemm_nt<<<g_qkv, blk, 0, stream>>>(h, Wk, nullptr, kh, NN, DIM, DIM, 1.f, 0, 1);
    gemm_nt<<<g_qkv, blk, 0, stream>>>(h, Wv, nullptr, vh, NN, DIM, DIM, 1.f, 0, 1);
    // Vsum per (h,d)
    vsum_part<<<64, blk, 0, stream>>>(vh, vpart);
    vsum_final<<<1, blk, 0, stream>>>(vpart, vsumh);
    // sparsity structure of A (deterministic order)
    build_nz2<<<NN, blk, 0, stream>>>(A, nzidx, nzav, nzcnt);
    // attention
    attn2<<<NN, blk, 0, stream>>>(qh, kh, vh, vsumh, nzidx, nzav, nzcnt, ao);
    // output projection + residual
    gemm_nt<<<g_qkv, blk, 0, stream>>>(ao, Wo, h, y, NN, DIM, DIM, 1.f, 0, 0);
    // BN1
    colreduce_partial<<<256, blk, 0, stream>>>(y, ps, pq);
    colreduce_final<<<1, blk, 0, stream>>>(ps, pq, mean1, rstd1);
    bn_apply<<<NN, blk, 0, stream>>>(y, mean1, rstd1, g1, b1, h2);
    // FFN + residual
    gemm_nt<<<g_ffn1, blk, 0, stream>>>(h2, W1, nullptr, t, NN, DFF, DIM, 1.f, 1, 0);
    gemm_nt<<<g_qkv, blk, 0, stream>>>(t, W2, h2, y2, NN, DIM, DFF, 1.f, 0, 0);
    // BN2 -> d_out
    colreduce_partial<<<256, blk, 0, stream>>>(y2, ps, pq);
    colreduce_final<<<1, blk, 0, stream>>>(ps, pq, mean2, rstd2);
    bn_apply<<<NN, blk, 0, stream>>>(y2, mean2, rstd2, g2, b2, out);
}

// Round 3
// 159.467 us; speedup vs baseline: 2.5009x; 1.6673x over previous
//
#include <hip/hip_runtime.h>
#include <math.h>

#define NN 4096        // nodes
#define DIM 256        // hidden
#define NHEAD 8
#define HDIM 32
#define DFF 512
#define CAP 128        // max tracked nonzeros per row (mean ~41, P(>128) ~ 0)
#define EPS_BN 1e-5f
#define QSCALE 0.0625f // D^-0.5
#define MB (1u << 20)

typedef __attribute__((ext_vector_type(8))) short short8;
typedef __attribute__((ext_vector_type(4))) float f32x4;

__device__ inline ushort f2bf(float x) {   // RNE float->bf16 (finite inputs)
    unsigned u = __builtin_bit_cast(unsigned, x);
    unsigned r = u + 0x7FFF + ((u >> 16) & 1);
    return (ushort)(r >> 16);
}

// ---------------- fp32 -> bf16 conversion (h + all weights, one launch) ----
// virtual segments of 2048 elems/block: h:512 | Wq:32 | Wk:32 | Wv:32 | Wo:32 | W1:64 | W2:64
__global__ __launch_bounds__(256) void convert_bf(
    const float* __restrict__ s0, const float* __restrict__ s1,
    const float* __restrict__ s2, const float* __restrict__ s3,
    const float* __restrict__ s4, const float* __restrict__ s5,
    const float* __restrict__ s6,
    ushort* d0, ushort* d1, ushort* d2, ushort* d3,
    ushort* d4, ushort* d5, ushort* d6)
{
    int b = blockIdx.x;
    const float* s; ushort* d; int off;
    if      (b < 512) { s = s0; d = d0; off = b; }
    else if (b < 544) { s = s1; d = d1; off = b - 512; }
    else if (b < 576) { s = s2; d = d2; off = b - 544; }
    else if (b < 608) { s = s3; d = d3; off = b - 576; }
    else if (b < 640) { s = s4; d = d4; off = b - 608; }
    else if (b < 704) { s = s5; d = d5; off = b - 640; }
    else              { s = s6; d = d6; off = b - 704; }
    size_t base = (size_t)off * 2048 + (size_t)threadIdx.x * 8;
    float4 f0 = *(const float4*)(s + base);
    float4 f1 = *(const float4*)(s + base + 4);
    uint4 u;
    u.x = (unsigned)f2bf(f0.x) | ((unsigned)f2bf(f0.y) << 16);
    u.y = (unsigned)f2bf(f0.z) | ((unsigned)f2bf(f0.w) << 16);
    u.z = (unsigned)f2bf(f1.x) | ((unsigned)f2bf(f1.y) << 16);
    u.w = (unsigned)f2bf(f1.z) | ((unsigned)f2bf(f1.w) << 16);
    *(uint4*)(d + base) = u;
}

// ---------------- bf16 MFMA GEMM: C = scale*(A @ B^T) [+resid] [relu] ------
// A [M,K] bf16 row-major, B [Nn,K] bf16 row-major. Tile 64x64xBK64, 4 waves.
// Cf: optional fp32 out; Cb: optional bf16 out. qkvscale: scale=QSCALE for col<256.
#define LDP 88   // padded LDS row stride (ushort): 176B = 16B-aligned, 2-way banks
__global__ __launch_bounds__(256) void gemm_bf(
    const ushort* __restrict__ A, const ushort* __restrict__ B,
    const float* __restrict__ resid, float* __restrict__ Cf,
    ushort* __restrict__ Cb, int M, int Nn, int K, int relu, int qkvscale)
{
    __shared__ ushort As[64][LDP];
    __shared__ ushort Bs[64][LDP];
    int tid = threadIdx.x;
    int lane = tid & 63, w = tid >> 6;
    int wm = (w >> 1) * 32, wn = (w & 1) * 32;
    int m0 = blockIdx.y * 64, n0 = blockIdx.x * 64;
    int l15 = lane & 15, lk = lane >> 4;

    int srow = tid >> 3;            // 0..31
    int scol = (tid & 7) * 8;       // 0..56 step 8
    const ushort* Ag = A + (size_t)(m0 + srow) * K + scol;
    const ushort* Bg = B + (size_t)(n0 + srow) * K + scol;

    f32x4 acc[2][2] = {};
    for (int k0 = 0; k0 < K; k0 += 64) {
        uint4 ga0 = *(const uint4*)(Ag + k0);
        uint4 ga1 = *(const uint4*)(Ag + k0 + (size_t)32 * K);
        uint4 gb0 = *(const uint4*)(Bg + k0);
        uint4 gb1 = *(const uint4*)(Bg + k0 + (size_t)32 * K);
        __syncthreads();
        *(uint4*)&As[srow][scol]      = ga0;
        *(uint4*)&As[srow + 32][scol] = ga1;
        *(uint4*)&Bs[srow][scol]      = gb0;
        *(uint4*)&Bs[srow + 32][scol] = gb1;
        __syncthreads();
        #pragma unroll
        for (int ks = 0; ks < 2; ++ks) {
            int kc = ks * 32 + lk * 8;
            short8 a0 = *(const short8*)&As[wm      + l15][kc];
            short8 a1 = *(const short8*)&As[wm + 16 + l15][kc];
            short8 b0 = *(const short8*)&Bs[wn      + l15][kc];
            short8 b1 = *(const short8*)&Bs[wn + 16 + l15][kc];
            acc[0][0] = __builtin_amdgcn_mfma_f32_16x16x32_bf16(a0, b0, acc[0][0], 0, 0, 0);
            acc[0][1] = __builtin_amdgcn_mfma_f32_16x16x32_bf16(a0, b1, acc[0][1], 0, 0, 0);
            acc[1][0] = __builtin_amdgcn_mfma_f32_16x16x32_bf16(a1, b0, acc[1][0], 0, 0, 0);
            acc[1][1] = __builtin_amdgcn_mfma_f32_16x16x32_bf16(a1, b1, acc[1][1], 0, 0, 0);
        }
    }
    #pragma unroll
    for (int mt = 0; mt < 2; ++mt) {
        #pragma unroll
        for (int nt = 0; nt < 2; ++nt) {
            int col = n0 + wn + nt * 16 + l15;
            float scl = qkvscale ? (col < 256 ? QSCALE : 1.f) : 1.f;
            #pragma unroll
            for (int i = 0; i < 4; ++i) {
                int row = m0 + wm + mt * 16 + lk * 4 + i;
                float v = acc[mt][nt][i] * scl;
                if (resid) v += resid[(size_t)row * Nn + col];
                if (relu)  v = fmaxf(v, 0.f);
                if (Cf) Cf[(size_t)row * Nn + col] = v;
                if (Cb) Cb[(size_t)row * Nn + col] = f2bf(v);
            }
        }
    }
}

// ---------------- permute qkv [N][768] -> qh/kh/vh [8][N][32] fp32 ---------
__global__ __launch_bounds__(256) void permute_qkv(
    const float* __restrict__ qkv, float* __restrict__ qh,
    float* __restrict__ kh, float* __restrict__ vh)
{
    int n = blockIdx.x, t = threadIdx.x;
    int h = t >> 5, d = t & 31;
    const float* row = qkv + (size_t)n * 768;
    float qv = row[d * 8 + h];
    float kv = row[256 + d * 8 + h];
    float vv = row[512 + d * 8 + h];
    size_t o = ((size_t)h * NN + n) * HDIM + d;
    qh[o] = qv; kh[o] = kv; vh[o] = vv;
}

// ---------------- column reduce for BN (sum + sumsq) -----------------------
__global__ __launch_bounds__(256) void colreduce_partial(
    const float* __restrict__ x, float* __restrict__ ps, float* __restrict__ pq)
{
    int c = threadIdx.x, b = blockIdx.x;
    float s = 0.f, q = 0.f;
    for (int r = 0; r < 16; ++r) {
        float v = x[(size_t)(b * 16 + r) * DIM + c];
        s += v;
        q += v * v;
    }
    ps[b * DIM + c] = s;
    pq[b * DIM + c] = q;
}

__global__ __launch_bounds__(256) void colreduce_final(
    const float* __restrict__ ps, const float* __restrict__ pq,
    float* __restrict__ mean, float* __restrict__ rstd)
{
    int c = threadIdx.x;
    float s = 0.f, q = 0.f;
    for (int b = 0; b < 256; ++b) {
        s += ps[b * DIM + c];
        q += pq[b * DIM + c];
    }
    float m = s * (1.f / NN);
    float var = q * (1.f / NN) - m * m;
    mean[c] = m;
    rstd[c] = rsqrtf(var + EPS_BN);
}

// BN1: writes fp32 (residual source) + bf16 (FFN1 GEMM operand)
__global__ __launch_bounds__(256) void bn_apply2(
    const float* __restrict__ x, const float* __restrict__ mean,
    const float* __restrict__ rstd, const float* __restrict__ g,
    const float* __restrict__ bsh, float* __restrict__ outf,
    ushort* __restrict__ outb)
{
    int c = threadIdx.x;
    size_t i = (size_t)blockIdx.x * DIM + c;
    float v = (x[i] - mean[c]) * rstd[c] * g[c] + bsh[c];
    outf[i] = v;
    outb[i] = f2bf(v);
}

__global__ __launch_bounds__(256) void bn_apply(
    const float* __restrict__ x, const float* __restrict__ mean,
    const float* __restrict__ rstd, const float* __restrict__ g,
    const float* __restrict__ bsh, float* __restrict__ out)
{
    int c = threadIdx.x;
    size_t i = (size_t)blockIdx.x * DIM + c;
    out[i] = (x[i] - mean[c]) * rstd[c] * g[c] + bsh[c];
}

// ---------------- vsum over head-major v -----------------------------------
__global__ __launch_bounds__(256) void vsum_part(
    const float* __restrict__ vh, float* __restrict__ part)
{
    __shared__ float red[8][32];
    int h = blockIdx.x & 7, cchunk = blockIdx.x >> 3;
    int d = threadIdx.x & 31, r = threadIdx.x >> 5;
    const float* vp = vh + ((size_t)h * NN + cchunk * 512) * HDIM + d;
    float s = 0.f;
    for (int m = r; m < 512; m += 8) s += vp[(size_t)m * HDIM];
    red[r][d] = s;
    __syncthreads();
    if (r == 0) {
        float t = 0.f;
        #pragma unroll
        for (int i = 0; i < 8; ++i) t += red[i][d];
        part[(size_t)blockIdx.x * 32 + d] = t;
    }
}

__global__ __launch_bounds__(256) void vsum_final(
    const float* __restrict__ part, float* __restrict__ vsumh)
{
    int tid = threadIdx.x;
    int h = tid >> 5, d = tid & 31;
    float s = 0.f;
    #pragma unroll
    for (int c = 0; c < 8; ++c) s += part[(size_t)((c << 3) | h) * 32 + d];
    vsumh[tid] = s;   // [h][d]
}

// ---------------- deterministic per-row nonzero list of A ------------------
__global__ __launch_bounds__(256) void build_nz2(
    const float* __restrict__ A, int* __restrict__ idx,
    float* __restrict__ av, int* __restrict__ cnt)
{
    __shared__ int scan[256];
    int tid = threadIdx.x, n = blockIdx.x;
    const float* row = A + (size_t)n * NN;
    int base = tid * 16;
    int c = 0;
    #pragma unroll
    for (int i = 0; i < 16; ++i) c += (row[base + i] != 0.f) ? 1 : 0;
    scan[tid] = c;
    __syncthreads();
    for (int off = 1; off < 256; off <<= 1) {
        int t = (tid >= off) ? scan[tid - off] : 0;
        __syncthreads();
        scan[tid] += t;
        __syncthreads();
    }
    int pos = scan[tid] - c;
    int total = scan[255];
    #pragma unroll
    for (int i = 0; i < 16; ++i) {
        float a = row[base + i];
        if (a != 0.f && pos < CAP) {
            idx[n * CAP + pos] = base + i;
            av[n * CAP + pos] = a;
            ++pos;
        }
    }
    if (tid == 0) cnt[n] = min(total, CAP);
}

// ---------------- sparse masked attention (bf16 output) --------------------
__global__ __launch_bounds__(256) void attn2(
    const float* __restrict__ qh, const float* __restrict__ kh,
    const float* __restrict__ vh, const float* __restrict__ vsumh,
    const int* __restrict__ idx, const float* __restrict__ av,
    const int* __restrict__ cnt, ushort* __restrict__ out)
{
    __shared__ float sQ[NHEAD][HDIM];
    __shared__ int   sIdx[CAP];
    __shared__ float sAv[CAP];
    __shared__ float sS[CAP][NHEAD];
    __shared__ float red[32][NHEAD];
    __shared__ float sE0[NHEAD], sMx[NHEAD], sRd[NHEAD];

    int tid = threadIdx.x, n = blockIdx.x;
    int nnz = cnt[n];
    {
        int h = tid >> 5, d = tid & 31;
        sQ[h][d] = qh[((size_t)h * NN + n) * HDIM + d];
    }
    for (int j = tid; j < nnz; j += 256) {
        sIdx[j] = idx[n * CAP + j];
        sAv[j]  = av[n * CAP + j];
    }
    __syncthreads();

    int h8 = tid & 7, jr = tid >> 3;
    float4 qreg[8];
    #pragma unroll
    for (int t = 0; t < 8; ++t) qreg[t] = ((const float4*)sQ[h8])[t];
    float lmax = 0.0f;
    for (int jb = 0; jb < nnz; jb += 32) {
        int j = jb + jr;
        if (j < nnz) {
            int m = sIdx[j];
            const float4* kp = (const float4*)(kh + ((size_t)h8 * NN + m) * HDIM);
            float s = 0.f;
            #pragma unroll
            for (int t = 0; t < 8; ++t) {
                float4 kv = kp[t];
                s += kv.x * qreg[t].x + kv.y * qreg[t].y
                   + kv.z * qreg[t].z + kv.w * qreg[t].w;
            }
            s *= sAv[j];
            sS[j][h8] = s;
            lmax = fmaxf(lmax, s);
        }
    }
    red[jr][h8] = lmax;
    __syncthreads();
    if (jr < 16) red[jr][h8] = fmaxf(red[jr][h8], red[jr + 16][h8]);
    __syncthreads();
    if (jr < 8)  red[jr][h8] = fmaxf(red[jr][h8], red[jr + 8][h8]);
    __syncthreads();
    if (jr < 4)  red[jr][h8] = fmaxf(red[jr][h8], red[jr + 4][h8]);
    __syncthreads();
    if (jr < 2)  red[jr][h8] = fmaxf(red[jr][h8], red[jr + 2][h8]);
    __syncthreads();
    if (jr == 0) {
        float mx = fmaxf(red[0][h8], red[1][h8]);
        sMx[h8] = mx;
        sE0[h8] = __expf(-mx);
    }
    __syncthreads();

    float mx = sMx[h8], e0 = sE0[h8];
    float lsum = 0.f;
    for (int jb = 0; jb < nnz; jb += 32) {
        int j = jb + jr;
        if (j < nnz) {
            float w = __expf(sS[j][h8] - mx);
            lsum += w;
            sS[j][h8] = w - e0;
        }
    }
    red[jr][h8] = lsum;
    __syncthreads();
    if (jr < 16) red[jr][h8] += red[jr + 16][h8];
    __syncthreads();
    if (jr < 8)  red[jr][h8] += red[jr + 8][h8];
    __syncthreads();
    if (jr < 4)  red[jr][h8] += red[jr + 4][h8];
    __syncthreads();
    if (jr < 2)  red[jr][h8] += red[jr + 2][h8];
    __syncthreads();
    if (jr == 0) {
        float den = red[0][h8] + red[1][h8] + (float)(NN - nnz) * e0;
        sRd[h8] = 1.0f / den;
    }
    __syncthreads();

    int h = tid >> 5, d = tid & 31;
    const float* vp = vh + (size_t)h * NN * HDIM + d;
    float acc = 0.f;
    #pragma unroll 4
    for (int j = 0; j < nnz; ++j) {
        acc += sS[j][h] * vp[(size_t)sIdx[j] * HDIM];
    }
    float r = (acc + sE0[h] * vsumh[h * HDIM + d]) * sRd[h];
    out[(size_t)n * DIM + d * NHEAD + h] = f2bf(r);
}

// ---------------------------------------------------------------------------
extern "C" void kernel_launch(void* const* d_in, const int* in_sizes, int n_in,
                              void* d_out, int out_size, void* d_ws, size_t ws_size,
                              hipStream_t stream)
{
    const float* A  = (const float*)d_in[0];
    const float* h  = (const float*)d_in[1];
    const float* Wq = (const float*)d_in[2];
    const float* Wk = (const float*)d_in[3];
    const float* Wv = (const float*)d_in[4];
    const float* Wo = (const float*)d_in[5];
    const float* g1 = (const float*)d_in[6];
    const float* b1 = (const float*)d_in[7];
    const float* g2 = (const float*)d_in[8];
    const float* b2 = (const float*)d_in[9];
    const float* W1 = (const float*)d_in[10];
    const float* W2 = (const float*)d_in[11];
    float* out = (float*)d_out;
    char* w = (char*)d_ws;

    // ---- workspace layout (overlays exploit disjoint lifetimes) ----
    float*  qkv   = (float*)(w);                 // [0,12M)  QKV gemm -> permute
    int*    nzidx = (int*)(w);                   // [0,2M)   build_nz -> attn2
    float*  nzav  = (float*)(w + 2 * MB);        // [2M,4M)
    int*    nzcnt = (int*)(w + 4 * MB);          // 16 KB
    float*  y     = (float*)(w + 5 * MB);        // [5M,9M)  Wo out -> bn1
    float*  y2    = y;                           //          FFN2 out -> bn2
    float*  h2f   = (float*)(w + 9 * MB);        // [9M,13M) bn1 -> FFN2 resid
    float*  qh    = (float*)(w + 13 * MB);       // 4 MB
    float*  kh    = (float*)(w + 17 * MB);       // 4 MB
    float*  vh    = (float*)(w + 21 * MB);       // 4 MB
    ushort* t_bf  = (ushort*)qh;                 // 4 MB, FFN1 -> FFN2 (qh dead)
    ushort* h_bf  = (ushort*)(w + 25 * MB);      // 2 MB
    ushort* wqkv  = (ushort*)(w + 27 * MB);      // 384 KB (q|k|v rows)
    ushort* wo_b  = (ushort*)(w + 27 * MB + 384 * 1024);  // 128 KB
    ushort* w1_b  = (ushort*)(w + 27 * MB + 512 * 1024);  // 256 KB
    ushort* w2_b  = (ushort*)(w + 27 * MB + 768 * 1024);  // 256 KB
    ushort* ao_bf = (ushort*)(w + 28 * MB);      // 2 MB
    ushort* h2b   = (ushort*)(w + 30 * MB);      // 2 MB
    float*  ps    = (float*)(w + 32 * MB);       // 256 KB
    float*  pq    = (float*)(w + 32 * MB + 256 * 1024);
    float*  mean1 = (float*)(w + 32 * MB + 512 * 1024);
    float*  rstd1 = mean1 + 256;
    float*  mean2 = mean1 + 512;
    float*  rstd2 = mean1 + 768;
    float*  vsumh = mean1 + 1024;
    float*  vpart = mean1 + 2048;                // 8 KB

    dim3 blk(256);

    // bf16 conversions: h, Wq|Wk|Wv (fused 768x256), Wo, W1, W2
    convert_bf<<<768, blk, 0, stream>>>(h, Wq, Wk, Wv, Wo, W1, W2,
        h_bf, wqkv, wqkv + 65536, wqkv + 131072, wo_b, w1_b, w2_b);
    // fused QKV gemm: [4096,768] = h_bf @ wqkv^T (q cols pre-scaled)
    gemm_bf<<<dim3(12, 64), blk, 0, stream>>>(h_bf, wqkv, nullptr, qkv, nullptr,
                                              NN, 768, DIM, 0, 1);
    permute_qkv<<<NN, blk, 0, stream>>>(qkv, qh, kh, vh);
    vsum_part<<<64, blk, 0, stream>>>(vh, vpart);
    vsum_final<<<1, blk, 0, stream>>>(vpart, vsumh);
    build_nz2<<<NN, blk, 0, stream>>>(A, nzidx, nzav, nzcnt);
    attn2<<<NN, blk, 0, stream>>>(qh, kh, vh, vsumh, nzidx, nzav, nzcnt, ao_bf);
    // Wo projection + residual(h)
    gemm_bf<<<dim3(4, 64), blk, 0, stream>>>(ao_bf, wo_b, h, y, nullptr,
                                             NN, DIM, DIM, 0, 0);
    // BN1
    colreduce_partial<<<256, blk, 0, stream>>>(y, ps, pq);
    colreduce_final<<<1, blk, 0, stream>>>(ps, pq, mean1, rstd1);
    bn_apply2<<<NN, blk, 0, stream>>>(y, mean1, rstd1, g1, b1, h2f, h2b);
    // FFN
    gemm_bf<<<dim3(8, 64), blk, 0, stream>>>(h2b, w1_b, nullptr, nullptr, t_bf,
                                             NN, DFF, DIM, 1, 0);
    gemm_bf<<<dim3(4, 64), blk, 0, stream>>>(t_bf, w2_b, h2f, y2, nullptr,
                                             NN, DIM, DFF, 0, 0);
    // BN2 -> out
    colreduce_partial<<<256, blk, 0, stream>>>(y2, ps, pq);
    colreduce_final<<<1, blk, 0, stream>>>(ps, pq, mean2, rstd2);
    bn_apply<<<NN, blk, 0, stream>>>(y2, mean2, rstd2, g2, b2, out);
}

// Round 4
// 143.647 us; speedup vs baseline: 2.7763x; 1.1101x over previous
//
#include <hip/hip_runtime.h>
#include <math.h>

#define NN 4096        // nodes
#define DIM 256        // hidden
#define NHEAD 8
#define HDIM 32
#define DFF 512
#define CAP 128        // max nonzeros per row (mean ~41, max ~75 at p=.01)
#define EPS_BN 1e-5f
#define QSCALE 0.0625f // D^-0.5
#define MB (1u << 20)

typedef __attribute__((ext_vector_type(8))) short short8;
typedef __attribute__((ext_vector_type(4))) float f32x4;

__device__ inline ushort f2bf(float x) {   // RNE float->bf16
    unsigned u = __builtin_bit_cast(unsigned, x);
    unsigned r = u + 0x7FFF + ((u >> 16) & 1);
    return (ushort)(r >> 16);
}
__device__ inline float bf2f(ushort u) {
    return __builtin_bit_cast(float, (unsigned)u << 16);
}
__device__ inline float bflo(unsigned u) { return __builtin_bit_cast(float, u << 16); }
__device__ inline float bfhi(unsigned u) { return __builtin_bit_cast(float, u & 0xFFFF0000u); }

// ---------------- prep: fp32->bf16 converts (blocks 0..767) ----------------
//                  + deterministic nz-list build (blocks 768..4863)
__global__ __launch_bounds__(256) void prep(
    const float* __restrict__ s0, const float* __restrict__ s1,
    const float* __restrict__ s2, const float* __restrict__ s3,
    const float* __restrict__ s4, const float* __restrict__ s5,
    const float* __restrict__ s6,
    ushort* d0, ushort* d1, ushort* d2, ushort* d3,
    ushort* d4, ushort* d5, ushort* d6,
    const float* __restrict__ A, int* __restrict__ idx,
    float* __restrict__ av, int* __restrict__ cnt)
{
    __shared__ int scan[256];
    int b = blockIdx.x, tid = threadIdx.x;
    if (b < 768) {
        const float* s; ushort* d; int off;
        if      (b < 512) { s = s0; d = d0; off = b; }
        else if (b < 544) { s = s1; d = d1; off = b - 512; }
        else if (b < 576) { s = s2; d = d2; off = b - 544; }
        else if (b < 608) { s = s3; d = d3; off = b - 576; }
        else if (b < 640) { s = s4; d = d4; off = b - 608; }
        else if (b < 704) { s = s5; d = d5; off = b - 640; }
        else              { s = s6; d = d6; off = b - 704; }
        size_t base = (size_t)off * 2048 + (size_t)tid * 8;
        float4 f0 = *(const float4*)(s + base);
        float4 f1 = *(const float4*)(s + base + 4);
        uint4 u;
        u.x = (unsigned)f2bf(f0.x) | ((unsigned)f2bf(f0.y) << 16);
        u.y = (unsigned)f2bf(f0.z) | ((unsigned)f2bf(f0.w) << 16);
        u.z = (unsigned)f2bf(f1.x) | ((unsigned)f2bf(f1.y) << 16);
        u.w = (unsigned)f2bf(f1.z) | ((unsigned)f2bf(f1.w) << 16);
        *(uint4*)(d + base) = u;
        return;
    }
    int n = b - 768;
    const float* row = A + (size_t)n * NN;
    // coalesced: chunk i, lane tid -> cols i*1024 + tid*4 .. +3
    float4 vals[4];
    int c = 0;
    #pragma unroll
    for (int i = 0; i < 4; ++i) {
        vals[i] = *(const float4*)(row + i * 1024 + tid * 4);
        c += (vals[i].x != 0.f) + (vals[i].y != 0.f)
           + (vals[i].z != 0.f) + (vals[i].w != 0.f);
    }
    scan[tid] = c;
    __syncthreads();
    for (int off = 1; off < 256; off <<= 1) {
        int t = (tid >= off) ? scan[tid - off] : 0;
        __syncthreads();
        scan[tid] += t;
        __syncthreads();
    }
    int pos = scan[tid] - c;       // exclusive prefix
    int total = scan[255];
    #pragma unroll
    for (int i = 0; i < 4; ++i) {
        int cb = i * 1024 + tid * 4;
        float4 v = vals[i];
        if (v.x != 0.f && pos < CAP) { idx[n*CAP+pos] = cb;     av[n*CAP+pos] = v.x; ++pos; }
        if (v.y != 0.f && pos < CAP) { idx[n*CAP+pos] = cb + 1; av[n*CAP+pos] = v.y; ++pos; }
        if (v.z != 0.f && pos < CAP) { idx[n*CAP+pos] = cb + 2; av[n*CAP+pos] = v.z; ++pos; }
        if (v.w != 0.f && pos < CAP) { idx[n*CAP+pos] = cb + 3; av[n*CAP+pos] = v.w; ++pos; }
    }
    if (tid == 0) cnt[n] = min(total, CAP);
}

// ---------------- bf16 MFMA GEMM, multi-mode -------------------------------
// aMode 0: A bf16 [M,K].  aMode 1: A fp32 with on-load BN (scA/shA per col).
// storeMode 0: Cf fp32 (+resid). 1: Cb bf16 (relu opt). 2: qkv permuted bf16
//   (QSCALE on cols<256; q->qh, k/v interleaved ->kvh). 3: Cf fp32 with
//   residual recomputed as yres*scR+shR (Cf may alias yres; per-elem same-thread).
#define LDP 88
__global__ __launch_bounds__(256) void gemm_bf(
    const void* __restrict__ Aptr, const ushort* __restrict__ B,
    const float* __restrict__ scA, const float* __restrict__ shA,
    const float* __restrict__ resid,
    const float* yres, const float* __restrict__ scR, const float* __restrict__ shR,
    float* Cf, ushort* __restrict__ Cb,
    ushort* __restrict__ qh, ushort* __restrict__ kvh,
    int M, int Nn, int K, int aMode, int storeMode, int relu)
{
    __shared__ ushort As[64][LDP];
    __shared__ ushort Bs[64][LDP];
    int tid = threadIdx.x;
    int lane = tid & 63, w = tid >> 6;
    int wm = (w >> 1) * 32, wn = (w & 1) * 32;
    int m0 = blockIdx.y * 64, n0 = blockIdx.x * 64;
    int l15 = lane & 15, lk = lane >> 4;

    int srow = tid >> 3;            // 0..31
    int scol = (tid & 7) * 8;       // 0..56 step 8

    f32x4 acc[2][2] = {};
    for (int k0 = 0; k0 < K; k0 += 64) {
        uint4 ga0, ga1, gb0, gb1;
        const ushort* Bg = B + (size_t)(n0 + srow) * K + scol + k0;
        gb0 = *(const uint4*)Bg;
        gb1 = *(const uint4*)(Bg + (size_t)32 * K);
        if (aMode == 0) {
            const ushort* Ag = (const ushort*)Aptr + (size_t)(m0 + srow) * K + scol + k0;
            ga0 = *(const uint4*)Ag;
            ga1 = *(const uint4*)(Ag + (size_t)32 * K);
        } else {
            const float* Af = (const float*)Aptr + (size_t)(m0 + srow) * K + scol + k0;
            float4 sc0 = *(const float4*)(scA + k0 + scol);
            float4 sc1 = *(const float4*)(scA + k0 + scol + 4);
            float4 sh0 = *(const float4*)(shA + k0 + scol);
            float4 sh1 = *(const float4*)(shA + k0 + scol + 4);
            float4 a0 = *(const float4*)Af;
            float4 a1 = *(const float4*)(Af + 4);
            float4 b0 = *(const float4*)(Af + (size_t)32 * K);
            float4 b1 = *(const float4*)(Af + (size_t)32 * K + 4);
            ga0.x = (unsigned)f2bf(a0.x*sc0.x+sh0.x) | ((unsigned)f2bf(a0.y*sc0.y+sh0.y) << 16);
            ga0.y = (unsigned)f2bf(a0.z*sc0.z+sh0.z) | ((unsigned)f2bf(a0.w*sc0.w+sh0.w) << 16);
            ga0.z = (unsigned)f2bf(a1.x*sc1.x+sh1.x) | ((unsigned)f2bf(a1.y*sc1.y+sh1.y) << 16);
            ga0.w = (unsigned)f2bf(a1.z*sc1.z+sh1.z) | ((unsigned)f2bf(a1.w*sc1.w+sh1.w) << 16);
            ga1.x = (unsigned)f2bf(b0.x*sc0.x+sh0.x) | ((unsigned)f2bf(b0.y*sc0.y+sh0.y) << 16);
            ga1.y = (unsigned)f2bf(b0.z*sc0.z+sh0.z) | ((unsigned)f2bf(b0.w*sc0.w+sh0.w) << 16);
            ga1.z = (unsigned)f2bf(b1.x*sc1.x+sh1.x) | ((unsigned)f2bf(b1.y*sc1.y+sh1.y) << 16);
            ga1.w = (unsigned)f2bf(b1.z*sc1.z+sh1.z) | ((unsigned)f2bf(b1.w*sc1.w+sh1.w) << 16);
        }
        __syncthreads();
        *(uint4*)&As[srow][scol]      = ga0;
        *(uint4*)&As[srow + 32][scol] = ga1;
        *(uint4*)&Bs[srow][scol]      = gb0;
        *(uint4*)&Bs[srow + 32][scol] = gb1;
        __syncthreads();
        #pragma unroll
        for (int ks = 0; ks < 2; ++ks) {
            int kc = ks * 32 + lk * 8;
            short8 a0 = *(const short8*)&As[wm      + l15][kc];
            short8 a1 = *(const short8*)&As[wm + 16 + l15][kc];
            short8 b0 = *(const short8*)&Bs[wn      + l15][kc];
            short8 b1 = *(const short8*)&Bs[wn + 16 + l15][kc];
            acc[0][0] = __builtin_amdgcn_mfma_f32_16x16x32_bf16(a0, b0, acc[0][0], 0, 0, 0);
            acc[0][1] = __builtin_amdgcn_mfma_f32_16x16x32_bf16(a0, b1, acc[0][1], 0, 0, 0);
            acc[1][0] = __builtin_amdgcn_mfma_f32_16x16x32_bf16(a1, b0, acc[1][0], 0, 0, 0);
            acc[1][1] = __builtin_amdgcn_mfma_f32_16x16x32_bf16(a1, b1, acc[1][1], 0, 0, 0);
        }
    }
    #pragma unroll
    for (int mt = 0; mt < 2; ++mt) {
        #pragma unroll
        for (int nt = 0; nt < 2; ++nt) {
            int col = n0 + wn + nt * 16 + l15;
            #pragma unroll
            for (int i = 0; i < 4; ++i) {
                int row = m0 + wm + mt * 16 + lk * 4 + i;
                float v = acc[mt][nt][i];
                if (storeMode == 2) {
                    int seg = col >> 8, c = col & 255;
                    int hh = c & 7, dd = c >> 3;
                    if (seg == 0) v *= QSCALE;
                    ushort bv = f2bf(v);
                    if (seg == 0)
                        qh[((size_t)hh * NN + row) * HDIM + dd] = bv;
                    else
                        kvh[((size_t)hh * NN + row) * 64 + dd + ((seg == 2) ? 32 : 0)] = bv;
                } else if (storeMode == 0) {
                    if (resid) v += resid[(size_t)row * Nn + col];
                    Cf[(size_t)row * Nn + col] = v;
                } else if (storeMode == 1) {
                    if (relu) v = fmaxf(v, 0.f);
                    Cb[(size_t)row * Nn + col] = f2bf(v);
                } else { // 3
                    v += yres[(size_t)row * Nn + col] * scR[col] + shR[col];
                    Cf[(size_t)row * Nn + col] = v;
                }
            }
        }
    }
}

// ---------------- column reduce for BN -------------------------------------
__global__ __launch_bounds__(256) void colreduce_partial(
    const float* __restrict__ x, float* __restrict__ ps, float* __restrict__ pq)
{
    int c = threadIdx.x, b = blockIdx.x;
    float s = 0.f, q = 0.f;
    for (int r = 0; r < 16; ++r) {
        float v = x[(size_t)(b * 16 + r) * DIM + c];
        s += v;
        q += v * v;
    }
    ps[b * DIM + c] = s;
    pq[b * DIM + c] = q;
}

// -> scale/shift form: bn(x) = x*scale + shift
__global__ __launch_bounds__(256) void colreduce_final2(
    const float* __restrict__ ps, const float* __restrict__ pq,
    const float* __restrict__ g, const float* __restrict__ bsh,
    float* __restrict__ scale, float* __restrict__ shift)
{
    int c = threadIdx.x;
    float s = 0.f, q = 0.f;
    for (int b = 0; b < 256; ++b) {
        s += ps[b * DIM + c];
        q += pq[b * DIM + c];
    }
    float m = s * (1.f / NN);
    float var = q * (1.f / NN) - m * m;
    float rs = rsqrtf(var + EPS_BN);
    float sc = rs * g[c];
    scale[c] = sc;
    shift[c] = bsh[c] - m * sc;
}

__global__ __launch_bounds__(256) void bn_apply_fin(
    const float* __restrict__ x, const float* __restrict__ scale,
    const float* __restrict__ shift, float* __restrict__ out)
{
    int c = threadIdx.x;
    size_t i = (size_t)blockIdx.x * DIM + c;
    out[i] = x[i] * scale[c] + shift[c];
}

// ---------------- vsum over interleaved kvh (v halves) ---------------------
__global__ __launch_bounds__(256) void vsum_part(
    const ushort* __restrict__ kvh, float* __restrict__ part)
{
    __shared__ float red[8][32];
    int h = blockIdx.x & 7, ch = blockIdx.x >> 3;
    int d = threadIdx.x & 31, r = threadIdx.x >> 5;
    const ushort* vp = kvh + ((size_t)h * NN + ch * 512) * 64 + 32 + d;
    float s = 0.f;
    for (int m = r; m < 512; m += 8) s += bf2f(vp[(size_t)m * 64]);
    red[r][d] = s;
    __syncthreads();
    if (r == 0) {
        float t = 0.f;
        #pragma unroll
        for (int i = 0; i < 8; ++i) t += red[i][d];
        part[(size_t)blockIdx.x * 32 + d] = t;
    }
}

__global__ __launch_bounds__(256) void vsum_final(
    const float* __restrict__ part, float* __restrict__ vsumh)
{
    int tid = threadIdx.x;
    int h = tid >> 5, d = tid & 31;
    float s = 0.f;
    #pragma unroll
    for (int c = 0; c < 8; ++c) s += part[(size_t)((c << 3) | h) * 32 + d];
    vsumh[tid] = s;   // [h][d]
}

// ---------------- sparse masked attention (bf16 q/k/v, interleaved kv) -----
__global__ __launch_bounds__(256) void attn2(
    const ushort* __restrict__ qh, const ushort* __restrict__ kvh,
    const float* __restrict__ vsumh,
    const int* __restrict__ idx, const float* __restrict__ av,
    const int* __restrict__ cnt, ushort* __restrict__ out)
{
    __shared__ float sQ[NHEAD][HDIM];
    __shared__ int   sIdx[CAP];
    __shared__ float sAv[CAP];
    __shared__ float sS[CAP][NHEAD];
    __shared__ float red[32][NHEAD];
    __shared__ float sE0[NHEAD], sMx[NHEAD], sRd[NHEAD];

    int tid = threadIdx.x, n = blockIdx.x;
    int nnz = cnt[n];
    {
        int h = tid >> 5, d = tid & 31;
        sQ[h][d] = bf2f(qh[((size_t)h * NN + n) * HDIM + d]);
    }
    if (tid < nnz) {
        sIdx[tid] = idx[n * CAP + tid];
        sAv[tid]  = av[n * CAP + tid];
    }
    __syncthreads();

    // phase 1: scores; task (j = jb + tid>>3, h = tid&7)
    int h8 = tid & 7, jr = tid >> 3;
    float4 qreg[8];
    #pragma unroll
    for (int t = 0; t < 8; ++t) qreg[t] = ((const float4*)sQ[h8])[t];
    float lmax = 0.0f;                  // masked entries score exactly 0
    for (int jb = 0; jb < nnz; jb += 32) {
        int j = jb + jr;
        if (j < nnz) {
            int m = sIdx[j];
            const uint4* kp = (const uint4*)(kvh + ((size_t)h8 * NN + m) * 64);
            uint4 k0 = kp[0], k1 = kp[1], k2 = kp[2], k3 = kp[3];
            float s =
                bflo(k0.x)*qreg[0].x + bfhi(k0.x)*qreg[0].y +
                bflo(k0.y)*qreg[0].z + bfhi(k0.y)*qreg[0].w +
                bflo(k0.z)*qreg[1].x + bfhi(k0.z)*qreg[1].y +
                bflo(k0.w)*qreg[1].z + bfhi(k0.w)*qreg[1].w +
                bflo(k1.x)*qreg[2].x + bfhi(k1.x)*qreg[2].y +
                bflo(k1.y)*qreg[2].z + bfhi(k1.y)*qreg[2].w +
                bflo(k1.z)*qreg[3].x + bfhi(k1.z)*qreg[3].y +
                bflo(k1.w)*qreg[3].z + bfhi(k1.w)*qreg[3].w +
                bflo(k2.x)*qreg[4].x + bfhi(k2.x)*qreg[4].y +
                bflo(k2.y)*qreg[4].z + bfhi(k2.y)*qreg[4].w +
                bflo(k2.z)*qreg[5].x + bfhi(k2.z)*qreg[5].y +
                bflo(k2.w)*qreg[5].z + bfhi(k2.w)*qreg[5].w +
                bflo(k3.x)*qreg[6].x + bfhi(k3.x)*qreg[6].y +
                bflo(k3.y)*qreg[6].z + bfhi(k3.y)*qreg[6].w +
                bflo(k3.z)*qreg[7].x + bfhi(k3.z)*qreg[7].y +
                bflo(k3.w)*qreg[7].z + bfhi(k3.w)*qreg[7].w;
            s *= sAv[j];
            sS[j][h8] = s;
            lmax = fmaxf(lmax, s);
        }
    }
    red[jr][h8] = lmax;
    __syncthreads();
    if (jr < 16) red[jr][h8] = fmaxf(red[jr][h8], red[jr + 16][h8]);
    __syncthreads();
    if (jr < 8)  red[jr][h8] = fmaxf(red[jr][h8], red[jr + 8][h8]);
    __syncthreads();
    if (jr < 4)  red[jr][h8] = fmaxf(red[jr][h8], red[jr + 4][h8]);
    __syncthreads();
    if (jr < 2)  red[jr][h8] = fmaxf(red[jr][h8], red[jr + 2][h8]);
    __syncthreads();
    if (jr == 0) {
        float mx = fmaxf(red[0][h8], red[1][h8]);
        sMx[h8] = mx;
        sE0[h8] = __expf(-mx);
    }
    __syncthreads();

    // phase 2: weights + denom
    float mx = sMx[h8], e0 = sE0[h8];
    float lsum = 0.f;
    for (int jb = 0; jb < nnz; jb += 32) {
        int j = jb + jr;
        if (j < nnz) {
            float ww = __expf(sS[j][h8] - mx);
            lsum += ww;
            sS[j][h8] = ww - e0;
        }
    }
    red[jr][h8] = lsum;
    __syncthreads();
    if (jr < 16) red[jr][h8] += red[jr + 16][h8];
    __syncthreads();
    if (jr < 8)  red[jr][h8] += red[jr + 8][h8];
    __syncthreads();
    if (jr < 4)  red[jr][h8] += red[jr + 4][h8];
    __syncthreads();
    if (jr < 2)  red[jr][h8] += red[jr + 2][h8];
    __syncthreads();
    if (jr == 0) {
        float den = red[0][h8] + red[1][h8] + (float)(NN - nnz) * e0;
        sRd[h8] = 1.0f / den;
    }
    __syncthreads();

    // phase 3: output; thread (h = tid>>5, d = tid&31)
    int h = tid >> 5, d = tid & 31;
    const ushort* vp = kvh + (size_t)h * NN * 64 + 32 + d;
    float acc = 0.f;
    #pragma unroll 4
    for (int j = 0; j < nnz; ++j) {
        acc += sS[j][h] * bf2f(vp[(size_t)sIdx[j] * 64]);
    }
    float r = (acc + sE0[h] * vsumh[h * HDIM + d]) * sRd[h];
    out[(size_t)n * DIM + d * NHEAD + h] = f2bf(r);
}

// ---------------------------------------------------------------------------
extern "C" void kernel_launch(void* const* d_in, const int* in_sizes, int n_in,
                              void* d_out, int out_size, void* d_ws, size_t ws_size,
                              hipStream_t stream)
{
    const float* A  = (const float*)d_in[0];
    const float* h  = (const float*)d_in[1];
    const float* Wq = (const float*)d_in[2];
    const float* Wk = (const float*)d_in[3];
    const float* Wv = (const float*)d_in[4];
    const float* Wo = (const float*)d_in[5];
    const float* g1 = (const float*)d_in[6];
    const float* b1 = (const float*)d_in[7];
    const float* g2 = (const float*)d_in[8];
    const float* b2 = (const float*)d_in[9];
    const float* W1 = (const float*)d_in[10];
    const float* W2 = (const float*)d_in[11];
    float* out = (float*)d_out;
    char* w = (char*)d_ws;

    int*    nzidx  = (int*)(w);                  // [0,2M)
    float*  nzav   = (float*)(w + 2 * MB);       // [2M,4M)
    int*    nzcnt  = (int*)(w + 4 * MB);
    ushort* h_bf   = (ushort*)(w + 5 * MB);      // 2 MB
    ushort* wqkv   = (ushort*)(w + 7 * MB);      // 384 KB
    ushort* wo_b   = (ushort*)(w + 7 * MB + 384 * 1024);
    ushort* w1_b   = (ushort*)(w + 7 * MB + 512 * 1024);
    ushort* w2_b   = (ushort*)(w + 7 * MB + 768 * 1024);
    ushort* qh_bf  = (ushort*)(w + 8 * MB);      // 2 MB [8][4096][32]
    ushort* kvh    = (ushort*)(w + 10 * MB);     // 4 MB [8][4096][64] k|v
    ushort* ao_bf  = (ushort*)(w + 14 * MB);     // 2 MB
    float*  y      = (float*)(w + 16 * MB);      // 4 MB (Wo+res -> BN1 src; FFN2 aliases out)
    ushort* t_bf   = (ushort*)(w + 20 * MB);     // 4 MB FFN hidden
    float*  ps     = (float*)(w + 24 * MB);      // 256 KB
    float*  pq     = (float*)(w + 24 * MB + 256 * 1024);
    float*  scale1 = (float*)(w + 25 * MB);
    float*  shift1 = scale1 + 256;
    float*  scale2 = scale1 + 512;
    float*  shift2 = scale1 + 768;
    float*  vsumh  = scale1 + 1024;
    float*  vpart  = scale1 + 2048;              // 8 KB

    dim3 blk(256);

    // 1: convert (768 blocks) + build_nz (4096 blocks)
    prep<<<4864, blk, 0, stream>>>(h, Wq, Wk, Wv, Wo, W1, W2,
        h_bf, wqkv, wqkv + 65536, wqkv + 131072, wo_b, w1_b, w2_b,
        A, nzidx, nzav, nzcnt);
    // 2: fused QKV gemm, permuted bf16 epilogue -> qh_bf, kvh
    gemm_bf<<<dim3(12, 64), blk, 0, stream>>>(h_bf, wqkv,
        nullptr, nullptr, nullptr, nullptr, nullptr, nullptr,
        nullptr, nullptr, qh_bf, kvh, NN, 768, DIM, 0, 2, 0);
    // 3-4: vsum
    vsum_part<<<64, blk, 0, stream>>>(kvh, vpart);
    vsum_final<<<1, blk, 0, stream>>>(vpart, vsumh);
    // 5: attention
    attn2<<<NN, blk, 0, stream>>>(qh_bf, kvh, vsumh, nzidx, nzav, nzcnt, ao_bf);
    // 6: Wo projection + residual(h) -> y
    gemm_bf<<<dim3(4, 64), blk, 0, stream>>>(ao_bf, wo_b,
        nullptr, nullptr, h, nullptr, nullptr, nullptr,
        y, nullptr, nullptr, nullptr, NN, DIM, DIM, 0, 0, 0);
    // 7-8: BN1 stats -> scale1/shift1
    colreduce_partial<<<256, blk, 0, stream>>>(y, ps, pq);
    colreduce_final2<<<1, blk, 0, stream>>>(ps, pq, g1, b1, scale1, shift1);
    // 9: FFN1 with BN1 applied on A-load, relu, bf16 out
    gemm_bf<<<dim3(8, 64), blk, 0, stream>>>(y, w1_b,
        scale1, shift1, nullptr, nullptr, nullptr, nullptr,
        nullptr, t_bf, nullptr, nullptr, NN, DFF, DIM, 1, 1, 1);
    // 10: FFN2 + residual recomputed from y (in-place safe: per-elem same thread)
    gemm_bf<<<dim3(4, 64), blk, 0, stream>>>(t_bf, w2_b,
        nullptr, nullptr, nullptr, y, scale1, shift1,
        y, nullptr, nullptr, nullptr, NN, DIM, DFF, 0, 3, 0);
    // 11-12: BN2 stats -> scale2/shift2
    colreduce_partial<<<256, blk, 0, stream>>>(y, ps, pq);
    colreduce_final2<<<1, blk, 0, stream>>>(ps, pq, g2, b2, scale2, shift2);
    // 13: BN2 apply -> d_out
    bn_apply_fin<<<NN, blk, 0, stream>>>(y, scale2, shift2, out);
}

// Round 5
// 129.020 us; speedup vs baseline: 3.0911x; 1.1134x over previous
//
#include <hip/hip_runtime.h>
#include <math.h>

#define NN 4096        // nodes
#define DIM 256        // hidden
#define NHEAD 8
#define HDIM 32
#define DFF 512
#define CAP 128        // max nonzeros per row (mean ~41, max ~75 at p=.01)
#define EPS_BN 1e-5f
#define QSCALE 0.0625f // D^-0.5
#define MB (1u << 20)

typedef __attribute__((ext_vector_type(8))) short short8;
typedef __attribute__((ext_vector_type(4))) float f32x4;

__device__ inline ushort f2bf(float x) {   // RNE float->bf16
    unsigned u = __builtin_bit_cast(unsigned, x);
    unsigned r = u + 0x7FFF + ((u >> 16) & 1);
    return (ushort)(r >> 16);
}
__device__ inline float bf2f(ushort u) {
    return __builtin_bit_cast(float, (unsigned)u << 16);
}
__device__ inline float bflo(unsigned u) { return __builtin_bit_cast(float, u << 16); }
__device__ inline float bfhi(unsigned u) { return __builtin_bit_cast(float, u & 0xFFFF0000u); }

// ---------------- prep: fp32->bf16 converts (blocks 0..767) ----------------
// h-blocks (0..511) also emit per-block column-sum partials of h (for vsum).
// blocks 768..4863: deterministic nz-list build of A.
__global__ __launch_bounds__(256) void prep(
    const float* __restrict__ s0, const float* __restrict__ s1,
    const float* __restrict__ s2, const float* __restrict__ s3,
    const float* __restrict__ s4, const float* __restrict__ s5,
    const float* __restrict__ s6,
    ushort* d0, ushort* d1, ushort* d2, ushort* d3,
    ushort* d4, ushort* d5, ushort* d6,
    float* __restrict__ hpart,
    const float* __restrict__ A, int* __restrict__ idx,
    float* __restrict__ av, int* __restrict__ cnt)
{
    __shared__ int scan[256];
    __shared__ float sCS[8][256];
    int b = blockIdx.x, tid = threadIdx.x;
    if (b < 768) {
        const float* s; ushort* d; int off;
        if      (b < 512) { s = s0; d = d0; off = b; }
        else if (b < 544) { s = s1; d = d1; off = b - 512; }
        else if (b < 576) { s = s2; d = d2; off = b - 544; }
        else if (b < 608) { s = s3; d = d3; off = b - 576; }
        else if (b < 640) { s = s4; d = d4; off = b - 608; }
        else if (b < 704) { s = s5; d = d5; off = b - 640; }
        else              { s = s6; d = d6; off = b - 704; }
        size_t base = (size_t)off * 2048 + (size_t)tid * 8;
        float4 f0 = *(const float4*)(s + base);
        float4 f1 = *(const float4*)(s + base + 4);
        uint4 u;
        u.x = (unsigned)f2bf(f0.x) | ((unsigned)f2bf(f0.y) << 16);
        u.y = (unsigned)f2bf(f0.z) | ((unsigned)f2bf(f0.w) << 16);
        u.z = (unsigned)f2bf(f1.x) | ((unsigned)f2bf(f1.y) << 16);
        u.w = (unsigned)f2bf(f1.z) | ((unsigned)f2bf(f1.w) << 16);
        *(uint4*)(d + base) = u;
        if (b < 512) {
            // partial column sums of h over this block's 8 rows
            int r = tid >> 5, c0 = (tid & 31) * 8;
            sCS[r][c0+0] = f0.x; sCS[r][c0+1] = f0.y;
            sCS[r][c0+2] = f0.z; sCS[r][c0+3] = f0.w;
            sCS[r][c0+4] = f1.x; sCS[r][c0+5] = f1.y;
            sCS[r][c0+6] = f1.z; sCS[r][c0+7] = f1.w;
            __syncthreads();
            float s8 = 0.f;
            #pragma unroll
            for (int i = 0; i < 8; ++i) s8 += sCS[i][tid];
            hpart[(size_t)b * 256 + tid] = s8;
        }
        return;
    }
    int n = b - 768;
    const float* row = A + (size_t)n * NN;
    float4 vals[4];
    int c = 0;
    #pragma unroll
    for (int i = 0; i < 4; ++i) {
        vals[i] = *(const float4*)(row + i * 1024 + tid * 4);
        c += (vals[i].x != 0.f) + (vals[i].y != 0.f)
           + (vals[i].z != 0.f) + (vals[i].w != 0.f);
    }
    scan[tid] = c;
    __syncthreads();
    for (int off = 1; off < 256; off <<= 1) {
        int t = (tid >= off) ? scan[tid - off] : 0;
        __syncthreads();
        scan[tid] += t;
        __syncthreads();
    }
    int pos = scan[tid] - c;       // exclusive prefix
    int total = scan[255];
    #pragma unroll
    for (int i = 0; i < 4; ++i) {
        int cb = i * 1024 + tid * 4;
        float4 v = vals[i];
        if (v.x != 0.f && pos < CAP) { idx[n*CAP+pos] = cb;     av[n*CAP+pos] = v.x; ++pos; }
        if (v.y != 0.f && pos < CAP) { idx[n*CAP+pos] = cb + 1; av[n*CAP+pos] = v.y; ++pos; }
        if (v.z != 0.f && pos < CAP) { idx[n*CAP+pos] = cb + 2; av[n*CAP+pos] = v.z; ++pos; }
        if (v.w != 0.f && pos < CAP) { idx[n*CAP+pos] = cb + 3; av[n*CAP+pos] = v.w; ++pos; }
    }
    if (tid == 0) cnt[n] = min(total, CAP);
}

// ---------------- vsum via matvec: vsumh = colsum(h) @ Wv^T ----------------
__global__ __launch_bounds__(256) void vsum_mv(
    const float* __restrict__ hpart, const float* __restrict__ Wv,
    float* __restrict__ vsumh)
{
    __shared__ float cs[256];
    int tid = threadIdx.x;
    float s = 0.f;
    for (int p = 0; p < 512; ++p) s += hpart[(size_t)p * 256 + tid];
    cs[tid] = s;
    __syncthreads();
    // column c of v: v[:,c] = h @ Wv[c,:]
    const float* wr = Wv + (size_t)tid * 256;
    float acc = 0.f;
    #pragma unroll 4
    for (int k = 0; k < 256; ++k) acc += cs[k] * wr[k];
    int hh = tid & 7, dd = tid >> 3;
    vsumh[hh * HDIM + dd] = acc;
}

// ---------------- bf16 MFMA GEMM, multi-mode -------------------------------
// aMode 0: A bf16 [M,K].  aMode 1: A fp32 with on-load BN (scA/shA per col).
// storeMode 0: Cf fp32 (+resid). 1: Cb bf16 (relu opt). 2: qkv permuted bf16
//   (QSCALE on cols<256; q->qh, k/v interleaved ->kvh). 3: Cf fp32 with
//   residual recomputed as yres*scR+shR (Cf may alias yres).
// bnstat: emit per-block column sum/sumsq partials of stored value
//   (requires Nn==256, grid (4,64)) -> bnps/bnpq [64][256].
#define LDP 88
__global__ __launch_bounds__(256) void gemm_bf(
    const void* __restrict__ Aptr, const ushort* __restrict__ B,
    const float* __restrict__ scA, const float* __restrict__ shA,
    const float* __restrict__ resid,
    const float* yres, const float* __restrict__ scR, const float* __restrict__ shR,
    float* Cf, ushort* __restrict__ Cb,
    ushort* __restrict__ qh, ushort* __restrict__ kvh,
    float* __restrict__ bnps, float* __restrict__ bnpq,
    int M, int Nn, int K, int aMode, int storeMode, int relu, int bnstat)
{
    __shared__ ushort As[64][LDP];
    __shared__ ushort Bs[64][LDP];
    __shared__ float sRedS[8][64];
    __shared__ float sRedQ[8][64];
    int tid = threadIdx.x;
    int lane = tid & 63, w = tid >> 6;
    int wm = (w >> 1) * 32, wn = (w & 1) * 32;
    int m0 = blockIdx.y * 64, n0 = blockIdx.x * 64;
    int l15 = lane & 15, lk = lane >> 4;

    int srow = tid >> 3;            // 0..31
    int scol = (tid & 7) * 8;       // 0..56 step 8

    f32x4 acc[2][2] = {};
    for (int k0 = 0; k0 < K; k0 += 64) {
        uint4 ga0, ga1, gb0, gb1;
        const ushort* Bg = B + (size_t)(n0 + srow) * K + scol + k0;
        gb0 = *(const uint4*)Bg;
        gb1 = *(const uint4*)(Bg + (size_t)32 * K);
        if (aMode == 0) {
            const ushort* Ag = (const ushort*)Aptr + (size_t)(m0 + srow) * K + scol + k0;
            ga0 = *(const uint4*)Ag;
            ga1 = *(const uint4*)(Ag + (size_t)32 * K);
        } else {
            const float* Af = (const float*)Aptr + (size_t)(m0 + srow) * K + scol + k0;
            float4 sc0 = *(const float4*)(scA + k0 + scol);
            float4 sc1 = *(const float4*)(scA + k0 + scol + 4);
            float4 sh0 = *(const float4*)(shA + k0 + scol);
            float4 sh1 = *(const float4*)(shA + k0 + scol + 4);
            float4 a0 = *(const float4*)Af;
            float4 a1 = *(const float4*)(Af + 4);
            float4 b0 = *(const float4*)(Af + (size_t)32 * K);
            float4 b1 = *(const float4*)(Af + (size_t)32 * K + 4);
            ga0.x = (unsigned)f2bf(a0.x*sc0.x+sh0.x) | ((unsigned)f2bf(a0.y*sc0.y+sh0.y) << 16);
            ga0.y = (unsigned)f2bf(a0.z*sc0.z+sh0.z) | ((unsigned)f2bf(a0.w*sc0.w+sh0.w) << 16);
            ga0.z = (unsigned)f2bf(a1.x*sc1.x+sh1.x) | ((unsigned)f2bf(a1.y*sc1.y+sh1.y) << 16);
            ga0.w = (unsigned)f2bf(a1.z*sc1.z+sh1.z) | ((unsigned)f2bf(a1.w*sc1.w+sh1.w) << 16);
            ga1.x = (unsigned)f2bf(b0.x*sc0.x+sh0.x) | ((unsigned)f2bf(b0.y*sc0.y+sh0.y) << 16);
            ga1.y = (unsigned)f2bf(b0.z*sc0.z+sh0.z) | ((unsigned)f2bf(b0.w*sc0.w+sh0.w) << 16);
            ga1.z = (unsigned)f2bf(b1.x*sc1.x+sh1.x) | ((unsigned)f2bf(b1.y*sc1.y+sh1.y) << 16);
            ga1.w = (unsigned)f2bf(b1.z*sc1.z+sh1.z) | ((unsigned)f2bf(b1.w*sc1.w+sh1.w) << 16);
        }
        __syncthreads();
        *(uint4*)&As[srow][scol]      = ga0;
        *(uint4*)&As[srow + 32][scol] = ga1;
        *(uint4*)&Bs[srow][scol]      = gb0;
        *(uint4*)&Bs[srow + 32][scol] = gb1;
        __syncthreads();
        #pragma unroll
        for (int ks = 0; ks < 2; ++ks) {
            int kc = ks * 32 + lk * 8;
            short8 a0 = *(const short8*)&As[wm      + l15][kc];
            short8 a1 = *(const short8*)&As[wm + 16 + l15][kc];
            short8 b0 = *(const short8*)&Bs[wn      + l15][kc];
            short8 b1 = *(const short8*)&Bs[wn + 16 + l15][kc];
            acc[0][0] = __builtin_amdgcn_mfma_f32_16x16x32_bf16(a0, b0, acc[0][0], 0, 0, 0);
            acc[0][1] = __builtin_amdgcn_mfma_f32_16x16x32_bf16(a0, b1, acc[0][1], 0, 0, 0);
            acc[1][0] = __builtin_amdgcn_mfma_f32_16x16x32_bf16(a1, b0, acc[1][0], 0, 0, 0);
            acc[1][1] = __builtin_amdgcn_mfma_f32_16x16x32_bf16(a1, b1, acc[1][1], 0, 0, 0);
        }
    }
    float sp[2] = {0.f, 0.f}, qp[2] = {0.f, 0.f};
    #pragma unroll
    for (int mt = 0; mt < 2; ++mt) {
        #pragma unroll
        for (int nt = 0; nt < 2; ++nt) {
            int col = n0 + wn + nt * 16 + l15;
            #pragma unroll
            for (int i = 0; i < 4; ++i) {
                int row = m0 + wm + mt * 16 + lk * 4 + i;
                float v = acc[mt][nt][i];
                if (storeMode == 2) {
                    int seg = col >> 8, c = col & 255;
                    int hh = c & 7, dd = c >> 3;
                    if (seg == 0) v *= QSCALE;
                    ushort bv = f2bf(v);
                    if (seg == 0)
                        qh[((size_t)hh * NN + row) * HDIM + dd] = bv;
                    else
                        kvh[((size_t)hh * NN + row) * 64 + dd + ((seg == 2) ? 32 : 0)] = bv;
                } else if (storeMode == 0) {
                    if (resid) v += resid[(size_t)row * Nn + col];
                    Cf[(size_t)row * Nn + col] = v;
                } else if (storeMode == 1) {
                    if (relu) v = fmaxf(v, 0.f);
                    Cb[(size_t)row * Nn + col] = f2bf(v);
                } else { // 3
                    v += yres[(size_t)row * Nn + col] * scR[col] + shR[col];
                    Cf[(size_t)row * Nn + col] = v;
                }
                if (bnstat) { sp[nt] += v; qp[nt] += v * v; }
            }
        }
    }
    if (bnstat) {
        int slot = ((wm >> 5) << 2) | lk;
        sRedS[slot][wn + l15]      = sp[0];
        sRedQ[slot][wn + l15]      = qp[0];
        sRedS[slot][wn + 16 + l15] = sp[1];
        sRedQ[slot][wn + 16 + l15] = qp[1];
        __syncthreads();
        if (tid < 64) {
            float ss = 0.f, qq = 0.f;
            #pragma unroll
            for (int r = 0; r < 8; ++r) { ss += sRedS[r][tid]; qq += sRedQ[r][tid]; }
            bnps[(size_t)blockIdx.y * DIM + n0 + tid] = ss;
            bnpq[(size_t)blockIdx.y * DIM + n0 + tid] = qq;
        }
    }
}

// ---------------- BN stats final: 64 partials -> scale/shift ---------------
__global__ __launch_bounds__(256) void colreduce_final2(
    const float* __restrict__ ps, const float* __restrict__ pq,
    const float* __restrict__ g, const float* __restrict__ bsh,
    float* __restrict__ scale, float* __restrict__ shift)
{
    int c = threadIdx.x;
    float s = 0.f, q = 0.f;
    #pragma unroll 4
    for (int b = 0; b < 64; ++b) {
        s += ps[b * DIM + c];
        q += pq[b * DIM + c];
    }
    float m = s * (1.f / NN);
    float var = q * (1.f / NN) - m * m;
    float rs = rsqrtf(var + EPS_BN);
    float sc = rs * g[c];
    scale[c] = sc;
    shift[c] = bsh[c] - m * sc;
}

__global__ __launch_bounds__(256) void bn_apply_fin(
    const float* __restrict__ x, const float* __restrict__ scale,
    const float* __restrict__ shift, float* __restrict__ out)
{
    int tid = threadIdx.x;
    size_t i = (size_t)blockIdx.x * 1024 + (size_t)tid * 4;
    int c = (tid * 4) & 255;
    float4 v = *(const float4*)(x + i);
    float4 sc = *(const float4*)(scale + c);
    float4 sh = *(const float4*)(shift + c);
    float4 r;
    r.x = v.x * sc.x + sh.x;
    r.y = v.y * sc.y + sh.y;
    r.z = v.z * sc.z + sh.z;
    r.w = v.w * sc.w + sh.w;
    *(float4*)(out + i) = r;
}

// ---------------- sparse masked attention (no-max-shift softmax) -----------
// Scores |s| <~ 2 (q pre-scaled, a in [0,1]) -> exp needs no max subtraction,
// so e0 = exp(0) = 1 exactly and the max pass disappears.
__global__ __launch_bounds__(256) void attn2(
    const ushort* __restrict__ qh, const ushort* __restrict__ kvh,
    const float* __restrict__ vsumh,
    const int* __restrict__ idx, const float* __restrict__ av,
    const int* __restrict__ cnt, ushort* __restrict__ out)
{
    __shared__ float sQ[NHEAD][HDIM];
    __shared__ int   sIdx[CAP];
    __shared__ float sAv[CAP];
    __shared__ float sS[CAP][NHEAD];   // (w - 1)
    __shared__ float red[32][NHEAD];
    __shared__ float sRd[NHEAD];

    int tid = threadIdx.x, n = blockIdx.x;
    int nnz = cnt[n];
    {
        int h = tid >> 5, d = tid & 31;
        sQ[h][d] = bf2f(qh[((size_t)h * NN + n) * HDIM + d]);
    }
    if (tid < nnz) {
        sIdx[tid] = idx[n * CAP + tid];
        sAv[tid]  = av[n * CAP + tid];
    }
    __syncthreads();

    // phase 1: scores + weights + denom; task (j = jb + tid>>3, h = tid&7)
    int h8 = tid & 7, jr = tid >> 3;
    float4 qreg[8];
    #pragma unroll
    for (int t = 0; t < 8; ++t) qreg[t] = ((const float4*)sQ[h8])[t];
    float lsum = 0.0f;
    for (int jb = 0; jb < nnz; jb += 32) {
        int j = jb + jr;
        if (j < nnz) {
            int m = sIdx[j];
            const uint4* kp = (const uint4*)(kvh + ((size_t)h8 * NN + m) * 64);
            uint4 k0 = kp[0], k1 = kp[1], k2 = kp[2], k3 = kp[3];
            float s =
                bflo(k0.x)*qreg[0].x + bfhi(k0.x)*qreg[0].y +
                bflo(k0.y)*qreg[0].z + bfhi(k0.y)*qreg[0].w +
                bflo(k0.z)*qreg[1].x + bfhi(k0.z)*qreg[1].y +
                bflo(k0.w)*qreg[1].z + bfhi(k0.w)*qreg[1].w +
                bflo(k1.x)*qreg[2].x + bfhi(k1.x)*qreg[2].y +
                bflo(k1.y)*qreg[2].z + bfhi(k1.y)*qreg[2].w +
                bflo(k1.z)*qreg[3].x + bfhi(k1.z)*qreg[3].y +
                bflo(k1.w)*qreg[3].z + bfhi(k1.w)*qreg[3].w +
                bflo(k2.x)*qreg[4].x + bfhi(k2.x)*qreg[4].y +
                bflo(k2.y)*qreg[4].z + bfhi(k2.y)*qreg[4].w +
                bflo(k2.z)*qreg[5].x + bfhi(k2.z)*qreg[5].y +
                bflo(k2.w)*qreg[5].z + bfhi(k2.w)*qreg[5].w +
                bflo(k3.x)*qreg[6].x + bfhi(k3.x)*qreg[6].y +
                bflo(k3.y)*qreg[6].z + bfhi(k3.y)*qreg[6].w +
                bflo(k3.z)*qreg[7].x + bfhi(k3.z)*qreg[7].y +
                bflo(k3.w)*qreg[7].z + bfhi(k3.w)*qreg[7].w;
            s *= sAv[j];
            float ww = __expf(s);
            sS[j][h8] = ww - 1.0f;
            lsum += ww;
        }
    }
    red[jr][h8] = lsum;
    __syncthreads();
    if (jr < 16) red[jr][h8] += red[jr + 16][h8];
    __syncthreads();
    if (jr < 8)  red[jr][h8] += red[jr + 8][h8];
    __syncthreads();
    if (jr < 4)  red[jr][h8] += red[jr + 4][h8];
    __syncthreads();
    if (jr < 2)  red[jr][h8] += red[jr + 2][h8];
    __syncthreads();
    if (jr == 0) {
        float den = red[0][h8] + red[1][h8] + (float)(NN - nnz);
        sRd[h8] = 1.0f / den;
    }
    __syncthreads();

    // phase 2: output; thread (h = tid>>5, d = tid&31)
    int h = tid >> 5, d = tid & 31;
    const ushort* vp = kvh + (size_t)h * NN * 64 + 32 + d;
    float acc = 0.f;
    #pragma unroll 4
    for (int j = 0; j < nnz; ++j) {
        acc += sS[j][h] * bf2f(vp[(size_t)sIdx[j] * 64]);
    }
    float r = (acc + vsumh[h * HDIM + d]) * sRd[h];
    out[(size_t)n * DIM + d * NHEAD + h] = f2bf(r);
}

// ---------------------------------------------------------------------------
extern "C" void kernel_launch(void* const* d_in, const int* in_sizes, int n_in,
                              void* d_out, int out_size, void* d_ws, size_t ws_size,
                              hipStream_t stream)
{
    const float* A  = (const float*)d_in[0];
    const float* h  = (const float*)d_in[1];
    const float* Wq = (const float*)d_in[2];
    const float* Wk = (const float*)d_in[3];
    const float* Wv = (const float*)d_in[4];
    const float* Wo = (const float*)d_in[5];
    const float* g1 = (const float*)d_in[6];
    const float* b1 = (const float*)d_in[7];
    const float* g2 = (const float*)d_in[8];
    const float* b2 = (const float*)d_in[9];
    const float* W1 = (const float*)d_in[10];
    const float* W2 = (const float*)d_in[11];
    float* out = (float*)d_out;
    char* w = (char*)d_ws;

    int*    nzidx  = (int*)(w);                  // [0,2M)
    float*  nzav   = (float*)(w + 2 * MB);       // [2M,4M)
    int*    nzcnt  = (int*)(w + 4 * MB);
    ushort* h_bf   = (ushort*)(w + 5 * MB);      // 2 MB
    ushort* wqkv   = (ushort*)(w + 7 * MB);      // 384 KB
    ushort* wo_b   = (ushort*)(w + 7 * MB + 384 * 1024);
    ushort* w1_b   = (ushort*)(w + 7 * MB + 512 * 1024);
    ushort* w2_b   = (ushort*)(w + 7 * MB + 768 * 1024);
    ushort* qh_bf  = (ushort*)(w + 8 * MB);      // 2 MB [8][4096][32]
    ushort* kvh    = (ushort*)(w + 10 * MB);     // 4 MB [8][4096][64] k|v
    ushort* ao_bf  = (ushort*)(w + 14 * MB);     // 2 MB
    float*  y      = (float*)(w + 16 * MB);      // 4 MB
    ushort* t_bf   = (ushort*)(w + 20 * MB);     // 4 MB FFN hidden
    float*  hpart  = (float*)(w + 24 * MB);      // 512 KB [512][256]
    float*  bnps   = (float*)(w + 25 * MB);      // 64 KB [64][256]
    float*  bnpq   = (float*)(w + 25 * MB + 64 * 1024);
    float*  scale1 = (float*)(w + 26 * MB);
    float*  shift1 = scale1 + 256;
    float*  scale2 = scale1 + 512;
    float*  shift2 = scale1 + 768;
    float*  vsumh  = scale1 + 1024;

    dim3 blk(256);

    // 1: convert + h colsum partials + build_nz
    prep<<<4864, blk, 0, stream>>>(h, Wq, Wk, Wv, Wo, W1, W2,
        h_bf, wqkv, wqkv + 65536, wqkv + 131072, wo_b, w1_b, w2_b,
        hpart, A, nzidx, nzav, nzcnt);
    // 2: vsumh = colsum(h) @ Wv^T (tiny)
    vsum_mv<<<1, blk, 0, stream>>>(hpart, Wv, vsumh);
    // 3: fused QKV gemm, permuted bf16 epilogue -> qh_bf, kvh
    gemm_bf<<<dim3(12, 64), blk, 0, stream>>>(h_bf, wqkv,
        nullptr, nullptr, nullptr, nullptr, nullptr, nullptr,
        nullptr, nullptr, qh_bf, kvh, nullptr, nullptr,
        NN, 768, DIM, 0, 2, 0, 0);
    // 4: attention
    attn2<<<NN, blk, 0, stream>>>(qh_bf, kvh, vsumh, nzidx, nzav, nzcnt, ao_bf);
    // 5: Wo projection + residual(h) -> y, with BN1 stat partials
    gemm_bf<<<dim3(4, 64), blk, 0, stream>>>(ao_bf, wo_b,
        nullptr, nullptr, h, nullptr, nullptr, nullptr,
        y, nullptr, nullptr, nullptr, bnps, bnpq,
        NN, DIM, DIM, 0, 0, 0, 1);
    // 6: BN1 -> scale1/shift1
    colreduce_final2<<<1, blk, 0, stream>>>(bnps, bnpq, g1, b1, scale1, shift1);
    // 7: FFN1 with BN1 applied on A-load, relu, bf16 out
    gemm_bf<<<dim3(8, 64), blk, 0, stream>>>(y, w1_b,
        scale1, shift1, nullptr, nullptr, nullptr, nullptr,
        nullptr, t_bf, nullptr, nullptr, nullptr, nullptr,
        NN, DFF, DIM, 1, 1, 1, 0);
    // 8: FFN2 + recomputed BN1 residual, in-place on y, with BN2 stat partials
    gemm_bf<<<dim3(4, 64), blk, 0, stream>>>(t_bf, w2_b,
        nullptr, nullptr, nullptr, y, scale1, shift1,
        y, nullptr, nullptr, nullptr, bnps, bnpq,
        NN, DIM, DFF, 0, 3, 0, 1);
    // 9: BN2 -> scale2/shift2
    colreduce_final2<<<1, blk, 0, stream>>>(bnps, bnpq, g2, b2, scale2, shift2);
    // 10: BN2 apply -> d_out
    bn_apply_fin<<<1024, blk, 0, stream>>>(y, scale2, shift2, out);
}